// Round 1
// 1653.254 us; speedup vs baseline: 1.3096x; 1.3096x over previous
//
#include <hip/hip_runtime.h>
#include <cstdint>
#include <cstddef>

#define BB 8
#define SS 2
#define TT 512
#define CC 2048
#define ND 1024
#define AD 16384
#define NN 256
#define AN 2048
#define NEGV -1e30f
#define NTH 1024   // fwd block threads == number of arc chunks per graph

// ---------------------------------------------------------------------------
// prep: counting sort of arcs by dst (CSR order), emitted as chunk-transposed
// SoA records (meta = src | pdf<<10 | dst<<21, w). Also builds the partial-
// slot tables for the segmented merge:
//   npart[j] = #chunks state j's arc run touches; pbeg = excl-scan(npart);
//   padj[j]  = pbeg[j] - (rowptr[j] >> LC)   (slot = padj[dst] + chunk).
// One block per graph, blockDim.x == N.
// ---------------------------------------------------------------------------
__global__ void prep_kernel(const int* __restrict__ src, const int* __restrict__ dst,
                            const int* __restrict__ pdf, const float* __restrict__ w,
                            unsigned* __restrict__ meta_t, float* __restrict__ w_t,
                            int* __restrict__ pbeg, int* __restrict__ padj,
                            int N, int A, int LC)
{
    __shared__ int cnt[1024];
    __shared__ int pos[1024];
    const int g = blockIdx.x;
    src += (size_t)g * A; dst += (size_t)g * A; pdf += (size_t)g * A; w += (size_t)g * A;
    meta_t += (size_t)g * A; w_t += (size_t)g * A;
    pbeg += (size_t)g * (N + 1); padj += (size_t)g * N;
    const int tid = threadIdx.x;
    cnt[tid] = 0;
    __syncthreads();
    for (int a = tid; a < A; a += blockDim.x) atomicAdd(&cnt[dst[a]], 1);
    __syncthreads();
    const int deg = cnt[tid];
    // inclusive scan of deg (Hillis-Steele) -> exclusive row offset r0
    pos[tid] = deg;
    __syncthreads();
    for (int off = 1; off < blockDim.x; off <<= 1) {
        int add = (tid >= off) ? pos[tid - off] : 0;
        __syncthreads();
        pos[tid] += add;
        __syncthreads();
    }
    const int r0 = pos[tid] - deg;
    // partial counts per state and their exclusive scan
    const int np = deg ? (((r0 + deg - 1) >> LC) - (r0 >> LC) + 1) : 0;
    __syncthreads();
    pos[tid] = np;
    __syncthreads();
    for (int off = 1; off < blockDim.x; off <<= 1) {
        int add = (tid >= off) ? pos[tid - off] : 0;
        __syncthreads();
        pos[tid] += add;
        __syncthreads();
    }
    const int pexcl = pos[tid] - np;
    pbeg[tid] = pexcl;
    if (tid == blockDim.x - 1) pbeg[N] = pexcl + np;
    padj[tid] = pexcl - (r0 >> LC);
    // scatter arcs grouped by dst into chunk-transposed SoA
    cnt[tid] = r0;
    __syncthreads();
    for (int a = tid; a < A; a += blockDim.x) {
        const int d2 = dst[a];
        const int p = atomicAdd(&cnt[d2], 1);
        const int l = p >> LC;              // chunk (= owning fwd thread)
        const int i = p & ((1 << LC) - 1);  // position within chunk
        meta_t[(size_t)i * NTH + l] =
            (unsigned)src[a] | ((unsigned)pdf[a] << 10) | ((unsigned)d2 << 21);
        w_t[(size_t)i * NTH + l] = w[a];
    }
}

// ---------------------------------------------------------------------------
// FSM forward, arc-parallel: thread l owns CH consecutive (dst-sorted) arcs,
// records register-resident for the whole t-loop. Per step:
//   phase 1: batched independent alpha/llh gathers + per-segment online LSE,
//            partials (m, ss) written to consecutive LDS slots
//   phase 2: state-owner thread merges its partials (same guarded rescale),
//            writes alpha[j] with reference semantics:
//              mc = max(m, NEG); s' = ss*exp(m-mc); new = mc + log(max(s',1e-30))
// ---------------------------------------------------------------------------
template<int CH>
__device__ void fsm_forward(int N,
    const float* __restrict__ rowbase, int L,
    const unsigned* __restrict__ meta_g, const float* __restrict__ w_g,
    const int* __restrict__ pbeg_g, const int* __restrict__ padj_g,
    const float* __restrict__ initv, const float* __restrict__ finalv,
    float* __restrict__ res,
    float* llh0, float* llh1, float* alpha_s, float* pm, float* ps)
{
    const int tid = threadIdx.x;
    // one-time: arc records -> registers (coalesced: element i of thread l at i*1024+l)
    unsigned meta[CH]; float wreg[CH];
#pragma unroll
    for (int i = 0; i < CH; ++i) {
        meta[i] = meta_g[i * NTH + tid];
        wreg[i] = w_g[i * NTH + tid];
    }
    unsigned segmask = 0;
#pragma unroll
    for (int i = 0; i < CH; ++i) {
        const int di = (int)(meta[i] >> 21);
        const int dn = (i + 1 < CH) ? (int)(meta[i + 1] >> 21) : -1;
        if (di != dn) segmask |= (1u << i);
    }
    const int slot0 = padj_g[meta[0] >> 21] + tid;  // slots are consecutive per thread
    const bool st = tid < N;
    int pb0 = 0, pb1 = 0; float fin = 0.f;
    if (st) {
        alpha_s[tid] = initv[tid];
        pb0 = pbeg_g[tid]; pb1 = pbeg_g[tid + 1];
        fin = finalv[tid];
    }
    if (L > 0) { llh0[tid] = rowbase[tid]; llh0[tid + 1024] = rowbase[tid + 1024]; }
    __syncthreads();

    constexpr int G = (CH < 8) ? CH : 8;   // gather/compute group (CH % G == 0)
    for (int t = 0; t < L; ++t) {
        float* cur = (t & 1) ? llh1 : llh0;
        float* nxt = (t & 1) ? llh0 : llh1;
        const bool pre = (t + 1 < L);
        float p0 = 0.f, p1 = 0.f;
        if (pre) {  // issue next llh row early; latency hides under phase 1
            const float* nb = rowbase + (size_t)(t + 1) * CC;
            p0 = nb[tid]; p1 = nb[tid + 1024];
        }
        // phase 1: segmented online logsumexp over this thread's chunk
        float m = -INFINITY, ss = 0.f;
        int sl = slot0;
#pragma unroll
        for (int i0 = 0; i0 < CH; i0 += G) {
            float av[G], lv[G];
#pragma unroll
            for (int gi = 0; gi < G; ++gi) {  // independent gathers, batch-issued
                const unsigned mt = meta[i0 + gi];
                av[gi] = alpha_s[mt & 1023u];
                lv[gi] = cur[(mt >> 10) & 2047u];
            }
#pragma unroll
            for (int gi = 0; gi < G; ++gi) {
                const float sc = av[gi] + wreg[i0 + gi] + lv[gi];
                const float d = sc - m;                 // first arc of seg: +inf
                const float e = __expf(-fabsf(d));      // exp(-inf) = 0
                if (d > 0.f) { ss = ss * e + 1.f; m = sc; }
                else         { ss += e; }
                if (segmask & (1u << (i0 + gi))) {      // segment ends here
                    pm[sl] = m; ps[sl] = ss; ++sl;
                    m = -INFINITY; ss = 0.f;
                }
            }
        }
        if (pre) { nxt[tid] = p0; nxt[tid + 1024] = p1; }
        __syncthreads();                                 // partials + alpha reads done
        // phase 2: owners merge partials (arc order preserved: slot order = chunk order)
        if (st) {
            float mm = -INFINITY, s2 = 0.f;
            for (int q = pb0; q < pb1; ++q) {            // <= ~4 iterations
                const float m2 = pm[q], sp = ps[q];
                const float d = m2 - mm;
                const float e = __expf(-fabsf(d));
                if (d > 0.f) { s2 = s2 * e + sp; mm = m2; }
                else         { s2 += sp * e; }
            }
            const float mc  = fmaxf(mm, NEGV);
            const float scs = s2 * __expf(mm - mc);      // mm=-inf (no arcs) -> 0
            alpha_s[tid] = mc + __logf(fmaxf(scs, 1e-30f));
        }
        __syncthreads();
    }
    // logsumexp(alpha + final), block-wide tree reduce
    const float v = st ? (alpha_s[tid] + fin) : -INFINITY;
    float* red = llh0;
    red[tid] = v;
    __syncthreads();
    for (int off = 512; off > 0; off >>= 1) {
        if (tid < off) red[tid] = fmaxf(red[tid], red[tid + off]);
        __syncthreads();
    }
    const float M = red[0];
    __syncthreads();
    red[tid] = __expf(v - M);
    __syncthreads();
    for (int off = 512; off > 0; off >>= 1) {
        if (tid < off) red[tid] += red[tid + off];
        __syncthreads();
    }
    if (tid == 0) *res = M + __logf(red[0]);
}

__global__ __launch_bounds__(1024) void fwd_kernel(
    const float* __restrict__ est, const int* __restrict__ seqlen,
    const unsigned* __restrict__ den_meta, const float* __restrict__ den_w,
    const int* __restrict__ den_pbeg, const int* __restrict__ den_padj,
    const float* __restrict__ den_init, const float* __restrict__ den_final,
    const unsigned* __restrict__ num_meta, const float* __restrict__ num_w,
    const int* __restrict__ num_pbeg, const int* __restrict__ num_padj,
    const float* __restrict__ num_init, const float* __restrict__ num_final,
    float* __restrict__ res)
{
    __shared__ float llh0[2048];
    __shared__ float llh1[2048];
    __shared__ float alpha[1024];
    __shared__ float pm[2048];   // partial count P <= N + 1023 < 2048
    __shared__ float ps[2048];
    const int bid = blockIdx.x;
    if (bid < 16) {
        // denominator: fsm index = s*8 + b, shared graph, llh row of (b, s)
        const int s = bid >> 3, b = bid & 7;
        const float* rowbase = est + (size_t)(b * SS + s) * TT * CC;
        const int L = seqlen[b * SS + s];
        fsm_forward<16>(ND, rowbase, L, den_meta, den_w, den_pbeg, den_padj,
                        den_init, den_final, &res[bid], llh0, llh1, alpha, pm, ps);
    } else {
        // numerator: q = p*16 + (s*8 + b); perm p in {0,1}; speaker used = p ? 1-s : s
        const int q = bid - 16;
        const int p = q >> 4, g = q & 15;
        const int s = g >> 3, b = g & 7;
        const int sp = p ? (1 - s) : s;
        const float* rowbase = est + (size_t)(b * SS + sp) * TT * CC;
        const int L = seqlen[b * SS + sp];
        fsm_forward<2>(NN, rowbase, L,
                       num_meta + (size_t)g * AN, num_w + (size_t)g * AN,
                       num_pbeg + (size_t)g * (NN + 1), num_padj + (size_t)g * NN,
                       num_init + (size_t)g * NN, num_final + (size_t)g * NN,
                       &res[16 + p * 16 + g], llh0, llh1, alpha, pm, ps);
    }
}

// res layout: [0..15] den (s*8+b), [16..31] num perm0, [32..47] num perm1
__global__ void finalize_kernel(const float* __restrict__ res, float* __restrict__ out)
{
    if (threadIdx.x == 0 && blockIdx.x == 0) {
        float loss = 0.f;
        for (int b = 0; b < BB; ++b) {
            const float den = res[b] + res[8 + b];
            const float n0  = res[16 + b] + res[16 + 8 + b];
            const float n1  = res[32 + b] + res[32 + 8 + b];
            const float nm  = fminf(n0, n1);
            loss += -(nm - den);
        }
        out[0] = loss;
    }
}

extern "C" void kernel_launch(void* const* d_in, const int* in_sizes, int n_in,
                              void* d_out, int out_size, void* d_ws, size_t ws_size,
                              hipStream_t stream)
{
    const float* est       = (const float*)d_in[0];
    const int*   seqlen    = (const int*)  d_in[1];
    const int*   den_src   = (const int*)  d_in[2];
    const int*   den_dst   = (const int*)  d_in[3];
    const int*   den_pdf   = (const int*)  d_in[4];
    const float* den_w     = (const float*)d_in[5];
    const float* den_init  = (const float*)d_in[6];
    const float* den_final = (const float*)d_in[7];
    const int*   num_src   = (const int*)  d_in[8];
    const int*   num_dst   = (const int*)  d_in[9];
    const int*   num_pdf   = (const int*)  d_in[10];
    const float* num_w     = (const float*)d_in[11];
    const float* num_init  = (const float*)d_in[12];
    const float* num_final = (const float*)d_in[13];

    char* ws = (char*)d_ws;
    unsigned* den_meta   = (unsigned*)(ws + 0);        //  65536 B -> 65536
    float*    den_wt     = (float*)   (ws + 65536);    //  65536 B -> 131072
    unsigned* num_meta   = (unsigned*)(ws + 131072);   // 131072 B -> 262144
    float*    num_wt     = (float*)   (ws + 262144);   // 131072 B -> 393216
    int*      den_pbeg   = (int*)     (ws + 393216);   //   4100 B -> 397316
    int*      num_pbeg   = (int*)     (ws + 397376);   //  16448 B -> 413824
    int*      den_padj   = (int*)     (ws + 413824);   //   4096 B -> 417920
    int*      num_padj   = (int*)     (ws + 417920);   //  16384 B -> 434304
    float*    res        = (float*)   (ws + 434304);   //    192 B

    // den: CH=16 (LC=4); num: CH=2 (LC=1)
    prep_kernel<<<1, 1024, 0, stream>>>(den_src, den_dst, den_pdf, den_w,
                                        den_meta, den_wt, den_pbeg, den_padj,
                                        ND, AD, 4);
    prep_kernel<<<16, 256, 0, stream>>>(num_src, num_dst, num_pdf, num_w,
                                        num_meta, num_wt, num_pbeg, num_padj,
                                        NN, AN, 1);

    fwd_kernel<<<48, 1024, 0, stream>>>(est, seqlen,
                                        den_meta, den_wt, den_pbeg, den_padj,
                                        den_init, den_final,
                                        num_meta, num_wt, num_pbeg, num_padj,
                                        num_init, num_final, res);

    finalize_kernel<<<1, 64, 0, stream>>>(res, (float*)d_out);
}

// Round 2
// 1514.552 us; speedup vs baseline: 1.4295x; 1.0916x over previous
//
#include <hip/hip_runtime.h>
#include <cstdint>
#include <cstddef>

#define BB 8
#define SS 2
#define TT 512
#define CC 2048
#define ND 1024
#define AD 16384
#define NN 256
#define AN 2048
#define NEGV -1e30f
#define NTH 1024   // fwd block threads == number of arc chunks per graph

// ---------------------------------------------------------------------------
// prep: counting sort of arcs by dst (CSR order), emitted as chunk-transposed
// SoA records (meta = src | pdf<<10 | dst<<21, w) for the fwd kernel, plus a
// CSR-ordered pdf array (pxi[p] = pdf) for the W-precompute kernel, plus the
// partial-slot tables for the segmented merge:
//   npart[j] = #chunks state j's arc run touches; pbeg = excl-scan(npart);
//   padj[j]  = pbeg[j] - (rowptr[j] >> LC)   (slot = padj[dst] + chunk).
// One block per graph, blockDim.x == N.
// ---------------------------------------------------------------------------
__global__ void prep_kernel(const int* __restrict__ src, const int* __restrict__ dst,
                            const int* __restrict__ pdf, const float* __restrict__ w,
                            unsigned* __restrict__ meta_t, float* __restrict__ w_t,
                            unsigned* __restrict__ pxi,
                            int* __restrict__ pbeg, int* __restrict__ padj,
                            int N, int A, int LC)
{
    __shared__ int cnt[1024];
    __shared__ int pos[1024];
    const int g = blockIdx.x;
    src += (size_t)g * A; dst += (size_t)g * A; pdf += (size_t)g * A; w += (size_t)g * A;
    meta_t += (size_t)g * A; w_t += (size_t)g * A; pxi += (size_t)g * A;
    pbeg += (size_t)g * (N + 1); padj += (size_t)g * N;
    const int tid = threadIdx.x;
    cnt[tid] = 0;
    __syncthreads();
    for (int a = tid; a < A; a += blockDim.x) atomicAdd(&cnt[dst[a]], 1);
    __syncthreads();
    const int deg = cnt[tid];
    // inclusive scan of deg (Hillis-Steele) -> exclusive row offset r0
    pos[tid] = deg;
    __syncthreads();
    for (int off = 1; off < blockDim.x; off <<= 1) {
        int add = (tid >= off) ? pos[tid - off] : 0;
        __syncthreads();
        pos[tid] += add;
        __syncthreads();
    }
    const int r0 = pos[tid] - deg;
    // partial counts per state and their exclusive scan
    const int np = deg ? (((r0 + deg - 1) >> LC) - (r0 >> LC) + 1) : 0;
    __syncthreads();
    pos[tid] = np;
    __syncthreads();
    for (int off = 1; off < blockDim.x; off <<= 1) {
        int add = (tid >= off) ? pos[tid - off] : 0;
        __syncthreads();
        pos[tid] += add;
        __syncthreads();
    }
    const int pexcl = pos[tid] - np;
    pbeg[tid] = pexcl;
    if (tid == blockDim.x - 1) pbeg[N] = pexcl + np;
    padj[tid] = pexcl - (r0 >> LC);
    // scatter arcs grouped by dst into chunk-transposed SoA (+ CSR-order pdf)
    cnt[tid] = r0;
    __syncthreads();
    for (int a = tid; a < A; a += blockDim.x) {
        const int d2 = dst[a];
        const int p = atomicAdd(&cnt[d2], 1);
        const int l = p >> LC;              // chunk (= owning fwd thread)
        const int i = p & ((1 << LC) - 1);  // position within chunk
        meta_t[(size_t)i * NTH + l] =
            (unsigned)src[a] | ((unsigned)pdf[a] << 10) | ((unsigned)d2 << 21);
        w_t[(size_t)i * NTH + l] = w[a];
        pxi[p] = (unsigned)pdf[a];          // CSR order == chunk-major (x*CH+i)
    }
}

// ---------------------------------------------------------------------------
// W precompute for one time tile: W[trel][inst][x][i] = llh_inst[t0+trel][pdf]
// for arc (x,i) in CSR/chunk order. llh row staged in LDS; gathers from LDS;
// coalesced float4 writes. Fully parallel: 48*Tt blocks of 256 threads.
//   den insts q=0..15  (s=q>>3, b=q&7), 16384 arcs each
//   num insts r=0..31  (g=r&15, p=r>>4), 2048 arcs each, pdf from graph g
// ---------------------------------------------------------------------------
__global__ __launch_bounds__(256) void wprep_kernel(
    const float* __restrict__ est,
    const unsigned* __restrict__ pxi_den, const unsigned* __restrict__ pxi_num,
    float* __restrict__ Wd, float* __restrict__ Wn, int t0, int Tt)
{
    __shared__ float row_s[CC];
    const int tid = threadIdx.x;
    int bid = blockIdx.x;
    if (bid < 16 * Tt) {
        const int q = bid & 15, trel = bid >> 4;
        const int t = t0 + trel;
        const int s = q >> 3, b = q & 7;
        const float* row = est + ((size_t)(b * SS + s) * TT + t) * CC;
        for (int k = tid; k < CC; k += 256) row_s[k] = row[k];
        __syncthreads();
        float4* out = (float4*)(Wd + (size_t)(trel * 16 + q) * (16 * 1024));
        const uint4* p4 = (const uint4*)pxi_den;
        for (int k = 0; k < 16; ++k) {
            const int o4 = k * 256 + tid;
            const uint4 pp = p4[o4];
            out[o4] = make_float4(row_s[pp.x], row_s[pp.y], row_s[pp.z], row_s[pp.w]);
        }
    } else {
        bid -= 16 * Tt;
        const int r = bid & 31, trel = bid >> 5;
        const int t = t0 + trel;
        const int g = r & 15, p = r >> 4;
        const int s = g >> 3, b = g & 7;
        const int sp = p ? (1 - s) : s;
        const float* row = est + ((size_t)(b * SS + sp) * TT + t) * CC;
        for (int k = tid; k < CC; k += 256) row_s[k] = row[k];
        __syncthreads();
        float4* out = (float4*)(Wn + (size_t)(trel * 32 + r) * (2 * 1024));
        const uint4* p4 = (const uint4*)(pxi_num + (size_t)g * AN);
        for (int k = 0; k < 2; ++k) {
            const int o4 = k * 256 + tid;
            const uint4 pp = p4[o4];
            out[o4] = make_float4(row_s[pp.x], row_s[pp.y], row_s[pp.z], row_s[pp.w]);
        }
    }
}

template<int CH>
__device__ inline void load_w_row(const float* __restrict__ p, float* dst)
{
    if constexpr (CH == 16) {
        const float4* p4 = (const float4*)p;
        const float4 a = p4[0], b = p4[1], c = p4[2], d = p4[3];
        dst[0]=a.x;  dst[1]=a.y;  dst[2]=a.z;  dst[3]=a.w;
        dst[4]=b.x;  dst[5]=b.y;  dst[6]=b.z;  dst[7]=b.w;
        dst[8]=c.x;  dst[9]=c.y;  dst[10]=c.z; dst[11]=c.w;
        dst[12]=d.x; dst[13]=d.y; dst[14]=d.z; dst[15]=d.w;
    } else {
        const float2 v = *(const float2*)p;
        dst[0] = v.x; dst[1] = v.y;
    }
}

// ---------------------------------------------------------------------------
// FSM forward over one time tile [t0, t0+Tt): thread l owns CH consecutive
// (dst-sorted) arcs, records register-resident. Per step:
//   phase 1: batched independent alpha LDS gathers; llh term comes from the
//            precomputed W stream (coalesced global, prefetched 1 step ahead);
//            per-segment online LSE, packed (m,ss) partials to LDS
//   phase 2: owner merges its <=4 partials (batch-loaded, clamped) with the
//            same guarded rescale; reference semantics preserved exactly:
//              sc = (alpha+w)+llh; mc=max(m,NEG); s'=ss*exp(m-mc);
//              new = mc+log(max(s',1e-30))
// alpha persists in global between tiles; final tile does the LSE reduce.
// ---------------------------------------------------------------------------
template<int CH>
__device__ void fsm_forward_tile(int N, int L, int t0, int Tt, bool first, bool last,
    const float* __restrict__ Wrow0, int wstride,
    const unsigned* __restrict__ meta_g, const float* __restrict__ w_g,
    const int* __restrict__ pbeg_g, const int* __restrict__ padj_g,
    const float* __restrict__ initv, const float* __restrict__ finalv,
    float* __restrict__ alpha_gl, float* __restrict__ res,
    float* alpha_s, float2* pk)
{
    const int tid = threadIdx.x;
    // arc records -> registers (coalesced: element i of thread l at i*1024+l)
    unsigned meta[CH]; float wreg[CH];
#pragma unroll
    for (int i = 0; i < CH; ++i) {
        meta[i] = meta_g[i * NTH + tid];
        wreg[i] = w_g[i * NTH + tid];
    }
    unsigned segmask = 0;
#pragma unroll
    for (int i = 0; i < CH; ++i) {
        const int di = (int)(meta[i] >> 21);
        const int dn = (i + 1 < CH) ? (int)(meta[i + 1] >> 21) : -1;
        if (di != dn) segmask |= (1u << i);
    }
    const int slot0 = padj_g[meta[0] >> 21] + tid;  // slots consecutive per thread
    const bool st = tid < N;
    int pb0 = 0, pb1 = 0; float fin = 0.f;
    if (st) {
        alpha_s[tid] = first ? initv[tid] : alpha_gl[tid];
        pb0 = pbeg_g[tid]; pb1 = pbeg_g[tid + 1];
        fin = finalv[tid];
    }
    int tb = L - t0; if (tb > Tt) tb = Tt; if (tb < 0) tb = 0;
    float wc[CH];
    if (tb > 0) load_w_row<CH>(Wrow0 + (size_t)tid * CH, wc);
    __syncthreads();

    constexpr int G = (CH < 8) ? CH : 8;   // gather/compute group (CH % G == 0)
    for (int trel = 0; trel < tb; ++trel) {
        const bool pre = (trel + 1 < tb);
        float wn[CH];
        if (pre)   // prefetch next step's W; latency hides under phase 1+2
            load_w_row<CH>(Wrow0 + (size_t)(trel + 1) * wstride + (size_t)tid * CH, wn);
        // phase 1: segmented online logsumexp over this thread's chunk
        float m = -INFINITY, ss = 0.f;
        int sl = slot0;
#pragma unroll
        for (int i0 = 0; i0 < CH; i0 += G) {
            float av[G];
#pragma unroll
            for (int gi = 0; gi < G; ++gi)   // independent gathers, batch-issued
                av[gi] = alpha_s[meta[i0 + gi] & 1023u];
#pragma unroll
            for (int gi = 0; gi < G; ++gi) {
                const float sc = (av[gi] + wreg[i0 + gi]) + wc[i0 + gi];
                const float d = sc - m;                 // first arc of seg: +inf
                const float e = __expf(-fabsf(d));      // exp(-inf) = 0
                if (d > 0.f) { ss = ss * e + 1.f; m = sc; }
                else         { ss += e; }
                if (segmask & (1u << (i0 + gi))) {      // segment ends here
                    pk[sl] = make_float2(m, ss); ++sl;
                    m = -INFINITY; ss = 0.f;
                }
            }
        }
        __syncthreads();                                 // partials + alpha reads done
        // phase 2: owner merges partials (slot order == arc order), batch-loaded
        if (st) {
            float mm, s2;
            const int cnt = pb1 - pb0;
            if (cnt > 0) {
                const float2 P0 = pk[pb0];
                const float2 P1 = pk[cnt > 1 ? pb0 + 1 : pb0];
                const float2 P2 = pk[cnt > 2 ? pb0 + 2 : pb0];
                const float2 P3 = pk[cnt > 3 ? pb0 + 3 : pb0];
                mm = P0.x; s2 = P0.y;
                if (cnt > 1) {
                    const float d = P1.x - mm; const float e = __expf(-fabsf(d));
                    if (d > 0.f) { s2 = s2 * e + P1.y; mm = P1.x; } else { s2 += P1.y * e; }
                }
                if (cnt > 2) {
                    const float d = P2.x - mm; const float e = __expf(-fabsf(d));
                    if (d > 0.f) { s2 = s2 * e + P2.y; mm = P2.x; } else { s2 += P2.y * e; }
                }
                if (cnt > 3) {
                    const float d = P3.x - mm; const float e = __expf(-fabsf(d));
                    if (d > 0.f) { s2 = s2 * e + P3.y; mm = P3.x; } else { s2 += P3.y * e; }
                }
                for (int q2 = pb0 + 4; q2 < pb1; ++q2) {  // rare (num graphs only)
                    const float2 Pq = pk[q2];
                    const float d = Pq.x - mm; const float e = __expf(-fabsf(d));
                    if (d > 0.f) { s2 = s2 * e + Pq.y; mm = Pq.x; } else { s2 += Pq.y * e; }
                }
                const float mc  = fmaxf(mm, NEGV);
                const float scs = s2 * __expf(mm - mc);
                alpha_s[tid] = mc + __logf(fmaxf(scs, 1e-30f));
            } else {
                alpha_s[tid] = NEGV + __logf(1e-30f);    // no in-arcs (matches ref)
            }
        }
        __syncthreads();
        if (pre) {
#pragma unroll
            for (int i = 0; i < CH; ++i) wc[i] = wn[i];
        }
    }

    if (last) {
        // logsumexp(alpha + final) over N states, block-wide tree reduce
        const float v = st ? (alpha_s[tid] + fin) : -INFINITY;
        float* red = (float*)pk;
        red[tid] = v;
        __syncthreads();
        for (int off = 512; off > 0; off >>= 1) {
            if (tid < off) red[tid] = fmaxf(red[tid], red[tid + off]);
            __syncthreads();
        }
        const float M = red[0];
        __syncthreads();
        red[tid] = __expf(v - M);
        __syncthreads();
        for (int off = 512; off > 0; off >>= 1) {
            if (tid < off) red[tid] += red[tid + off];
            __syncthreads();
        }
        if (tid == 0) *res = M + __logf(red[0]);
    } else if (st) {
        alpha_gl[tid] = alpha_s[tid];
    }
}

__global__ __launch_bounds__(1024) void fwd_kernel(
    const int* __restrict__ seqlen,
    const float* __restrict__ Wd, const float* __restrict__ Wn,
    const unsigned* __restrict__ den_meta, const float* __restrict__ den_w,
    const int* __restrict__ den_pbeg, const int* __restrict__ den_padj,
    const float* __restrict__ den_init, const float* __restrict__ den_final,
    const unsigned* __restrict__ num_meta, const float* __restrict__ num_w,
    const int* __restrict__ num_pbeg, const int* __restrict__ num_padj,
    const float* __restrict__ num_init, const float* __restrict__ num_final,
    float* __restrict__ alpha_g, float* __restrict__ res,
    int t0, int Tt, int last)
{
    __shared__ float alpha[1024];
    __shared__ float2 pk[2048];   // partial count P <= N + 1024 <= 2048
    const int bid = blockIdx.x;
    const bool first = (t0 == 0);
    if (bid < 16) {
        // denominator: inst q = s*8 + b, shared graph, llh row of (b, s)
        const int s = bid >> 3, b = bid & 7;
        const int L = seqlen[b * SS + s];
        fsm_forward_tile<16>(ND, L, t0, Tt, first, last != 0,
                             Wd + (size_t)bid * (16 * 1024), 16 * 16 * 1024,
                             den_meta, den_w, den_pbeg, den_padj,
                             den_init, den_final,
                             alpha_g + (size_t)bid * 1024, &res[bid], alpha, pk);
    } else {
        // numerator: q = p*16 + g; perm p; g = s*8+b; speaker used = p ? 1-s : s
        const int q = bid - 16;
        const int p = q >> 4, g = q & 15;
        const int s = g >> 3, b = g & 7;
        const int sp = p ? (1 - s) : s;
        const int L = seqlen[b * SS + sp];
        fsm_forward_tile<2>(NN, L, t0, Tt, first, last != 0,
                            Wn + (size_t)q * (2 * 1024), 32 * 2 * 1024,
                            num_meta + (size_t)g * AN, num_w + (size_t)g * AN,
                            num_pbeg + (size_t)g * (NN + 1), num_padj + (size_t)g * NN,
                            num_init + (size_t)g * NN, num_final + (size_t)g * NN,
                            alpha_g + (size_t)bid * 1024, &res[16 + q], alpha, pk);
    }
}

// res layout: [0..15] den (s*8+b), [16..31] num perm0, [32..47] num perm1
__global__ void finalize_kernel(const float* __restrict__ res, float* __restrict__ out)
{
    if (threadIdx.x == 0 && blockIdx.x == 0) {
        float loss = 0.f;
        for (int b = 0; b < BB; ++b) {
            const float den = res[b] + res[8 + b];
            const float n0  = res[16 + b] + res[16 + 8 + b];
            const float n1  = res[32 + b] + res[32 + 8 + b];
            const float nm  = fminf(n0, n1);
            loss += -(nm - den);
        }
        out[0] = loss;
    }
}

extern "C" void kernel_launch(void* const* d_in, const int* in_sizes, int n_in,
                              void* d_out, int out_size, void* d_ws, size_t ws_size,
                              hipStream_t stream)
{
    const float* est       = (const float*)d_in[0];
    const int*   seqlen    = (const int*)  d_in[1];
    const int*   den_src   = (const int*)  d_in[2];
    const int*   den_dst   = (const int*)  d_in[3];
    const int*   den_pdf   = (const int*)  d_in[4];
    const float* den_w     = (const float*)d_in[5];
    const float* den_init  = (const float*)d_in[6];
    const float* den_final = (const float*)d_in[7];
    const int*   num_src   = (const int*)  d_in[8];
    const int*   num_dst   = (const int*)  d_in[9];
    const int*   num_pdf   = (const int*)  d_in[10];
    const float* num_w     = (const float*)d_in[11];
    const float* num_init  = (const float*)d_in[12];
    const float* num_final = (const float*)d_in[13];

    char* ws = (char*)d_ws;
    unsigned* den_meta = (unsigned*)(ws + 0);        //  65536 -> 65536
    float*    den_wt   = (float*)   (ws + 65536);    //  65536 -> 131072
    unsigned* num_meta = (unsigned*)(ws + 131072);   // 131072 -> 262144
    float*    num_wt   = (float*)   (ws + 262144);   // 131072 -> 393216
    unsigned* den_pxi  = (unsigned*)(ws + 393216);   //  65536 -> 458752
    unsigned* num_pxi  = (unsigned*)(ws + 458752);   // 131072 -> 589824
    int*      den_pbeg = (int*)     (ws + 589824);   //   4100 -> 594176
    int*      num_pbeg = (int*)     (ws + 594176);   //  16448 -> 610816
    int*      den_padj = (int*)     (ws + 610816);   //   4096 -> 614912
    int*      num_padj = (int*)     (ws + 614912);   //  16384 -> 631296
    float*    alpha_g  = (float*)   (ws + 631296);   // 196608 -> 827904
    float*    res      = (float*)   (ws + 827904);   //    192 -> 828416
    const size_t fixed = 828416;

    // time-tile size for the W stream: Wd = Tt*16*16384*4 B, Wn = Tt*32*2048*4 B
    int Tt = 64;
    while (Tt > 4 && fixed + (size_t)Tt * 1310720u > ws_size) Tt >>= 1;
    float* Wd = (float*)(ws + fixed);
    float* Wn = Wd + (size_t)Tt * 16 * 16384;

    // den: CH=16 (LC=4); num: CH=2 (LC=1)
    prep_kernel<<<1, 1024, 0, stream>>>(den_src, den_dst, den_pdf, den_w,
                                        den_meta, den_wt, den_pxi,
                                        den_pbeg, den_padj, ND, AD, 4);
    prep_kernel<<<16, 256, 0, stream>>>(num_src, num_dst, num_pdf, num_w,
                                        num_meta, num_wt, num_pxi,
                                        num_pbeg, num_padj, NN, AN, 1);

    const int nt = TT / Tt;
    for (int k = 0; k < nt; ++k) {
        wprep_kernel<<<48 * Tt, 256, 0, stream>>>(est, den_pxi, num_pxi,
                                                  Wd, Wn, k * Tt, Tt);
        fwd_kernel<<<48, 1024, 0, stream>>>(seqlen, Wd, Wn,
                                            den_meta, den_wt, den_pbeg, den_padj,
                                            den_init, den_final,
                                            num_meta, num_wt, num_pbeg, num_padj,
                                            num_init, num_final,
                                            alpha_g, res, k * Tt, Tt,
                                            (k == nt - 1) ? 1 : 0);
    }

    finalize_kernel<<<1, 64, 0, stream>>>(res, (float*)d_out);
}